// Round 3
// baseline (205.054 us; speedup 1.0000x reference)
//
#include <hip/hip_runtime.h>

// B=4, P=2048, N=8192, QD=CD=INNER=512, HEADS=8, DH=64, HC=WC=32, L=1024
// STRIDE=8 -> 17x17 clipped rectangle mask

typedef __attribute__((ext_vector_type(8))) short bf16x8;
typedef __attribute__((ext_vector_type(4))) float f32x4;

#define SCL 0.18033688f   // 0.125 * log2(e): softmax in exp2 domain

__device__ __forceinline__ unsigned short f2bf(float x) {
  union { float f; unsigned int u; } v; v.f = x;
  unsigned int r = v.u + 0x7FFFu + ((v.u >> 16) & 1u);  // RNE
  return (unsigned short)(r >> 16);
}

__device__ __forceinline__ float fexp2(float x) {
#if __has_builtin(__builtin_amdgcn_exp2f)
  return __builtin_amdgcn_exp2f(x);
#else
  return exp2f(x);
#endif
}

// ---- prep: transpose weights to N-major bf16 (Wt[n][k] = W[k][n]) ----
__global__ __launch_bounds__(256) void prep_w(const float* __restrict__ Wq, const float* __restrict__ Wk,
                                              const float* __restrict__ Wv, const float* __restrict__ Wo,
                                              unsigned short* __restrict__ Wqt, unsigned short* __restrict__ Wkt,
                                              unsigned short* __restrict__ Wvt, unsigned short* __restrict__ Wot) {
  int i = blockIdx.x * 256 + threadIdx.x;     // < 4*512*512
  int wsel = i >> 18;
  int r = i & 262143;
  int k = r >> 9, n = r & 511;
  const float* W = (wsel == 0) ? Wq : (wsel == 1) ? Wk : (wsel == 2) ? Wv : Wo;
  unsigned short* Wt = (wsel == 0) ? Wqt : (wsel == 1) ? Wkt : (wsel == 2) ? Wvt : Wot;
  Wt[n * 512 + k] = f2bf(W[r]);
}

// ---- Q projection, fused input prep: Qb = bf16((feats + pos_emb[coords//8]) @ Wq) ----
// tile 64(M) x 128(N), BK=32, 4 waves (2x2 of 32x64)
__global__ __launch_bounds__(256) void gemm_q(const float* __restrict__ feats,
                                              const int* __restrict__ coords,
                                              const float* __restrict__ pos_emb,
                                              const unsigned short* __restrict__ Bt,
                                              unsigned short* __restrict__ C) {
  __shared__ unsigned short As[64][40];
  __shared__ unsigned short Bs[128][40];
  __shared__ int pidx[64];
  const int t = threadIdx.x, l = t & 63, wid = t >> 6;
  const int wr = (wid >> 1) << 5;   // 0 / 32
  const int wc = (wid & 1) << 6;    // 0 / 64
  const long tm = (long)blockIdx.x * 64;
  const long tn = (long)blockIdx.y * 128;
  if (t < 64) {
    long q = tm + t;
    pidx[t] = ((coords[2 * q] >> 3) << 6) + (coords[2 * q + 1] >> 3);
  }
  __syncthreads();
  f32x4 acc[2][4] = {};
  const int lr = l & 15, lk = (l >> 4) << 3;
  for (int k0 = 0; k0 < 512; k0 += 32) {
#pragma unroll
    for (int p = 0; p < 2; ++p) {               // A: 64x32 f32 + pos add
      int e = t + (p << 8);
      int row = e >> 3, kg = (e & 7) << 2;
      float4 a = *(const float4*)(feats + (tm + row) * 512 + k0 + kg);
      float4 pv = *(const float4*)(pos_emb + (size_t)pidx[row] * 512 + k0 + kg);
      uint2 o;
      o.x = (unsigned)f2bf(a.x + pv.x) | ((unsigned)f2bf(a.y + pv.y) << 16);
      o.y = (unsigned)f2bf(a.z + pv.z) | ((unsigned)f2bf(a.w + pv.w) << 16);
      *(uint2*)(&As[row][kg]) = o;
    }
#pragma unroll
    for (int p = 0; p < 2; ++p) {               // B: 128x32 bf16
      int e = t + (p << 8);
      int row = e >> 2, kg = (e & 3) << 3;
      *(int4*)(&Bs[row][kg]) = *(const int4*)(Bt + (tn + row) * 512 + k0 + kg);
    }
    __syncthreads();
    bf16x8 af[2], bfr[4];
#pragma unroll
    for (int i = 0; i < 2; ++i) af[i]  = *(const bf16x8*)(&As[wr + i * 16 + lr][lk]);
#pragma unroll
    for (int i = 0; i < 4; ++i) bfr[i] = *(const bf16x8*)(&Bs[wc + i * 16 + lr][lk]);
#pragma unroll
    for (int mi = 0; mi < 2; ++mi)
#pragma unroll
      for (int ni = 0; ni < 4; ++ni)
        acc[mi][ni] = __builtin_amdgcn_mfma_f32_16x16x32_bf16(af[mi], bfr[ni], acc[mi][ni], 0, 0, 0);
    __syncthreads();
  }
  const int lq = (l >> 4) << 2;
#pragma unroll
  for (int mi = 0; mi < 2; ++mi)
#pragma unroll
    for (int ni = 0; ni < 4; ++ni) {
      long col = tn + wc + ni * 16 + lr;
      long r0 = tm + wr + mi * 16 + lq;
#pragma unroll
      for (int r = 0; r < 4; ++r)
        C[(r0 + r) * 512 + col] = f2bf(acc[mi][ni][r]);
    }
}

// ---- fused K|V projection with input prep; V written transposed ----
// A rows: 4096 (b*1024+l). y-tile 0-3 -> K (row-major), 4-7 -> V (d-major transposed)
__global__ __launch_bounds__(256) void gemm_kv(const float* __restrict__ ctx,
                                               const float* __restrict__ ctx_pos,
                                               const unsigned short* __restrict__ Wkt,
                                               const unsigned short* __restrict__ Wvt,
                                               unsigned short* __restrict__ Kb,
                                               unsigned short* __restrict__ Vt) {
  __shared__ unsigned short As[64][40];
  __shared__ unsigned short Bs[128][40];
  const int t = threadIdx.x, l = t & 63, wid = t >> 6;
  const int wr = (wid >> 1) << 5;
  const int wc = (wid & 1) << 6;
  const long tm = (long)blockIdx.x * 64;
  const bool isV = blockIdx.y >= 4;
  const int nt = isV ? (blockIdx.y - 4) : blockIdx.y;
  const unsigned short* Bt = (isV ? Wvt : Wkt) + (long)nt * 128 * 512;
  f32x4 acc[2][4] = {};
  const int lr = l & 15, lk = (l >> 4) << 3;
  for (int k0 = 0; k0 < 512; k0 += 32) {
#pragma unroll
    for (int p = 0; p < 2; ++p) {               // A: ctx + ctx_pos
      int e = t + (p << 8);
      int row = e >> 3, kg = (e & 7) << 2;
      long ar = tm + row;
      float4 a = *(const float4*)(ctx + ar * 512 + k0 + kg);
      float4 pv = *(const float4*)(ctx_pos + (size_t)(ar & 1023) * 512 + k0 + kg);
      uint2 o;
      o.x = (unsigned)f2bf(a.x + pv.x) | ((unsigned)f2bf(a.y + pv.y) << 16);
      o.y = (unsigned)f2bf(a.z + pv.z) | ((unsigned)f2bf(a.w + pv.w) << 16);
      *(uint2*)(&As[row][kg]) = o;
    }
#pragma unroll
    for (int p = 0; p < 2; ++p) {
      int e = t + (p << 8);
      int row = e >> 2, kg = (e & 3) << 3;
      *(int4*)(&Bs[row][kg]) = *(const int4*)(Bt + (long)row * 512 + k0 + kg);
    }
    __syncthreads();
    bf16x8 af[2], bfr[4];
#pragma unroll
    for (int i = 0; i < 2; ++i) af[i]  = *(const bf16x8*)(&As[wr + i * 16 + lr][lk]);
#pragma unroll
    for (int i = 0; i < 4; ++i) bfr[i] = *(const bf16x8*)(&Bs[wc + i * 16 + lr][lk]);
#pragma unroll
    for (int mi = 0; mi < 2; ++mi)
#pragma unroll
      for (int ni = 0; ni < 4; ++ni)
        acc[mi][ni] = __builtin_amdgcn_mfma_f32_16x16x32_bf16(af[mi], bfr[ni], acc[mi][ni], 0, 0, 0);
    __syncthreads();
  }
  const int lq = (l >> 4) << 2;
#pragma unroll
  for (int mi = 0; mi < 2; ++mi)
#pragma unroll
    for (int ni = 0; ni < 4; ++ni) {
      int cn = nt * 128 + wc + ni * 16 + lr;      // 0..511 within K or V
      long r0 = tm + wr + mi * 16 + lq;
      if (!isV) {
#pragma unroll
        for (int r = 0; r < 4; ++r)
          Kb[(r0 + r) * 512 + cn] = f2bf(acc[mi][ni][r]);
      } else {
        int h = cn >> 6, d = cn & 63;
#pragma unroll
        for (int r = 0; r < 4; ++r) {
          long row = r0 + r;
          int b = (int)(row >> 10), j = (int)(row & 1023);
          Vt[(((long)(b * 8 + h) * 64) + d) * 1024 + j] = f2bf(acc[mi][ni][r]);
        }
      }
    }
}

// ---- MFMA masked flash attention: 16 rows/wave, grid (32, 32) ----
__global__ __launch_bounds__(256) void attn_mfma(const unsigned short* __restrict__ Qb,
                                                 const unsigned short* __restrict__ Kb,
                                                 const unsigned short* __restrict__ Vt,
                                                 const int* __restrict__ coords,
                                                 unsigned short* __restrict__ Abf) {
  __shared__ unsigned short Plds[4][16][72];
  const int t = threadIdx.x;
  const int w = t >> 6, l = t & 63;
  const int g = l >> 4, lc = l & 15;
  const int bh = blockIdx.y, b = bh >> 3, h = bh & 7;
  const long qrow0 = (long)b * 2048 + blockIdx.x * 64 + w * 16;

  // 32-bit row/col bitmasks for the 4 query-rows this lane reduces (rows g*4+r)
  int rm[4], cm[4];
#pragma unroll
  for (int r = 0; r < 4; ++r) {
    long qg = qrow0 + g * 4 + r;
    int cr = (int)rintf((float)coords[2 * qg] * 0.0625f);      // round-half-even = jnp.round
    int cc = (int)rintf((float)coords[2 * qg + 1] * 0.0625f);
    int rlo = max(0, cr - 8), rhi = min(31, cr + 8);
    int clo = max(0, cc - 8), chi = min(31, cc + 8);
    rm[r] = (int)((((unsigned)1 << (rhi - rlo + 1)) - 1) << rlo);
    cm[r] = (int)((((unsigned)1 << (chi - clo + 1)) - 1) << clo);
  }

  bf16x8 qfr[2];
#pragma unroll
  for (int dc = 0; dc < 2; ++dc)
    qfr[dc] = *(const bf16x8*)(Qb + (qrow0 + lc) * 512 + h * 64 + dc * 32 + g * 8);

  f32x4 po[4] = {};
  float m_run[4], l_run[4];
#pragma unroll
  for (int i = 0; i < 4; ++i) { m_run[i] = -1e30f; l_run[i] = 0.0f; }

  const unsigned short* Kbb = Kb + ((long)b * 1024) * 512 + h * 64;
  const unsigned short* Vtb = Vt + ((long)bh * 64) * 1024;

  for (int kb = 0; kb < 1024; kb += 64) {
    bf16x8 kfr[4][2];
#pragma unroll
    for (int kf = 0; kf < 4; ++kf)
#pragma unroll
      for (int dc = 0; dc < 2; ++dc)
        kfr[kf][dc] = *(const bf16x8*)(Kbb + (long)(kb + kf * 16 + lc) * 512 + dc * 32 + g * 8);
    bf16x8 vfr[4][2];
#pragma unroll
    for (int df = 0; df < 4; ++df)
#pragma unroll
      for (int kc = 0; kc < 2; ++kc)
        vfr[df][kc] = *(const bf16x8*)(Vtb + (long)(df * 16 + lc) * 1024 + kb + kc * 32 + g * 8);

    // S = Q K^T
    f32x4 sv[4];
#pragma unroll
    for (int kf = 0; kf < 4; ++kf) {
      f32x4 a = {};
      a = __builtin_amdgcn_mfma_f32_16x16x32_bf16(qfr[0], kfr[kf][0], a, 0, 0, 0);
      a = __builtin_amdgcn_mfma_f32_16x16x32_bf16(qfr[1], kfr[kf][1], a, 0, 0, 0);
      sv[kf] = a;
    }

    // mask (bitmask) + scale into exp2 domain
#pragma unroll
    for (int kf = 0; kf < 4; ++kf) {
      int j = kb + kf * 16 + lc;
      int jr = j >> 5, jc = j & 31;
#pragma unroll
      for (int r = 0; r < 4; ++r) {
        bool ok = ((rm[r] >> jr) & (cm[r] >> jc) & 1) != 0;
        sv[kf][r] = ok ? sv[kf][r] * SCL : -3.0e38f;
      }
    }

    // online softmax (exp2 domain); row = query in 16 lanes of group g
#pragma unroll
    for (int r = 0; r < 4; ++r) {
      float tm4 = fmaxf(fmaxf(sv[0][r], sv[1][r]), fmaxf(sv[2][r], sv[3][r]));
      tm4 = fmaxf(tm4, __shfl_xor(tm4, 1));
      tm4 = fmaxf(tm4, __shfl_xor(tm4, 2));
      tm4 = fmaxf(tm4, __shfl_xor(tm4, 4));
      tm4 = fmaxf(tm4, __shfl_xor(tm4, 8));
      float mn = fmaxf(m_run[r], tm4);
      float sc = fexp2(m_run[r] - mn);
      m_run[r] = mn;
      float ps = 0.0f;
#pragma unroll
      for (int kf = 0; kf < 4; ++kf) {
        float pe = fexp2(sv[kf][r] - mn);
        sv[kf][r] = pe;
        ps += pe;
      }
      ps += __shfl_xor(ps, 1); ps += __shfl_xor(ps, 2);
      ps += __shfl_xor(ps, 4); ps += __shfl_xor(ps, 8);
      l_run[r] = l_run[r] * sc + ps;
#pragma unroll
      for (int df = 0; df < 4; ++df) po[df][r] *= sc;
    }

    // P (C-layout) -> LDS -> A-layout (wave-private)
#pragma unroll
    for (int kf = 0; kf < 4; ++kf)
#pragma unroll
      for (int r = 0; r < 4; ++r)
        Plds[w][g * 4 + r][kf * 16 + lc] = f2bf(sv[kf][r]);

    bf16x8 pa[2];
#pragma unroll
    for (int kc = 0; kc < 2; ++kc)
      pa[kc] = *(const bf16x8*)(&Plds[w][lc][kc * 32 + g * 8]);
#pragma unroll
    for (int df = 0; df < 4; ++df) {
      po[df] = __builtin_amdgcn_mfma_f32_16x16x32_bf16(pa[0], vfr[df][0], po[df], 0, 0, 0);
      po[df] = __builtin_amdgcn_mfma_f32_16x16x32_bf16(pa[1], vfr[df][1], po[df], 0, 0, 0);
    }
  }

  // epilogue
#pragma unroll
  for (int r = 0; r < 4; ++r) {
    float inv = 1.0f / l_run[r];
    long qr = qrow0 + g * 4 + r;
#pragma unroll
    for (int df = 0; df < 4; ++df)
      Abf[qr * 512 + h * 64 + df * 16 + lc] = f2bf(po[df][r] * inv);
  }
}

// ---- output projection: out = Abf @ Wot^T + bo (fp32 out) ----
__global__ __launch_bounds__(256) void gemm_o(const unsigned short* __restrict__ A,
                                              const unsigned short* __restrict__ Bt,
                                              float* __restrict__ C,
                                              const float* __restrict__ bias) {
  __shared__ unsigned short As[64][40];
  __shared__ unsigned short Bs[128][40];
  const int t = threadIdx.x, l = t & 63, wid = t >> 6;
  const int wr = (wid >> 1) << 5;
  const int wc = (wid & 1) << 6;
  const long tm = (long)blockIdx.x * 64;
  const long tn = (long)blockIdx.y * 128;
  f32x4 acc[2][4] = {};
  const int lr = l & 15, lk = (l >> 4) << 3;
  for (int k0 = 0; k0 < 512; k0 += 32) {
    {
      int e = t;                                // A: 64x32 bf16, 1 pass int4
      int row = e >> 2, kg = (e & 3) << 3;
      if (row < 64)
        *(int4*)(&As[row][kg]) = *(const int4*)(A + (tm + row) * 512 + k0 + kg);
    }
#pragma unroll
    for (int p = 0; p < 2; ++p) {
      int e = t + (p << 8);
      int row = e >> 2, kg = (e & 3) << 3;
      *(int4*)(&Bs[row][kg]) = *(const int4*)(Bt + (tn + row) * 512 + k0 + kg);
    }
    __syncthreads();
    bf16x8 af[2], bfr[4];
#pragma unroll
    for (int i = 0; i < 2; ++i) af[i]  = *(const bf16x8*)(&As[wr + i * 16 + lr][lk]);
#pragma unroll
    for (int i = 0; i < 4; ++i) bfr[i] = *(const bf16x8*)(&Bs[wc + i * 16 + lr][lk]);
#pragma unroll
    for (int mi = 0; mi < 2; ++mi)
#pragma unroll
      for (int ni = 0; ni < 4; ++ni)
        acc[mi][ni] = __builtin_amdgcn_mfma_f32_16x16x32_bf16(af[mi], bfr[ni], acc[mi][ni], 0, 0, 0);
    __syncthreads();
  }
  const int lq = (l >> 4) << 2;
#pragma unroll
  for (int mi = 0; mi < 2; ++mi)
#pragma unroll
    for (int ni = 0; ni < 4; ++ni) {
      long col = tn + wc + ni * 16 + lr;
      float bv = bias[col];
      long r0 = tm + wr + mi * 16 + lq;
#pragma unroll
      for (int r = 0; r < 4; ++r)
        C[(r0 + r) * 512 + col] = acc[mi][ni][r] + bv;
    }
}

extern "C" void kernel_launch(void* const* d_in, const int* in_sizes, int n_in,
                              void* d_out, int out_size, void* d_ws, size_t ws_size,
                              hipStream_t stream) {
  (void)in_sizes; (void)n_in; (void)out_size; (void)ws_size;
  const float* feats   = (const float*)d_in[0];
  const int*   coords  = (const int*)d_in[1];
  const float* ctx     = (const float*)d_in[2];
  const float* Wq      = (const float*)d_in[3];
  const float* Wk      = (const float*)d_in[4];
  const float* Wv      = (const float*)d_in[5];
  const float* Wo      = (const float*)d_in[6];
  const float* bo      = (const float*)d_in[7];
  const float* pos_emb = (const float*)d_in[8];
  const float* ctx_pos = (const float*)d_in[9];
  float* out = (float*)d_out;
  char* ws = (char*)d_ws;

  unsigned short* Wqt = (unsigned short*)(ws);              //   524,288
  unsigned short* Wkt = (unsigned short*)(ws + 524288);
  unsigned short* Wvt = (unsigned short*)(ws + 1048576);
  unsigned short* Wot = (unsigned short*)(ws + 1572864);
  unsigned short* Qb  = (unsigned short*)(ws + 2097152);    // 8,388,608
  unsigned short* Kb  = (unsigned short*)(ws + 10485760);   // 4,194,304
  unsigned short* Vt  = (unsigned short*)(ws + 14680064);   // 4,194,304
  unsigned short* Abf = (unsigned short*)(ws + 18874368);   // 8,388,608 (end 27,262,976)

  prep_w <<<4096, 256, 0, stream>>>(Wq, Wk, Wv, Wo, Wqt, Wkt, Wvt, Wot);

  gemm_q <<<dim3(128, 4), 256, 0, stream>>>(feats, coords, pos_emb, Wqt, Qb);
  gemm_kv<<<dim3(64, 8),  256, 0, stream>>>(ctx, ctx_pos, Wkt, Wvt, Kb, Vt);

  attn_mfma<<<dim3(32, 32), 256, 0, stream>>>(Qb, Kb, Vt, coords, Abf);

  gemm_o <<<dim3(128, 4), 256, 0, stream>>>(Abf, Wot, out, bo);
}

// Round 4
// 147.955 us; speedup vs baseline: 1.3859x; 1.3859x over previous
//
#include <hip/hip_runtime.h>

// B=4, P=2048, N=8192, QD=CD=INNER=512, HEADS=8, DH=64, HC=WC=32, L=1024
// STRIDE=8 -> 17x17 clipped rectangle mask

typedef __attribute__((ext_vector_type(8))) short bf16x8;
typedef __attribute__((ext_vector_type(4))) float f32x4;

#define SCL 0.18033688f   // 0.125 * log2(e): softmax in exp2 domain

__device__ __forceinline__ unsigned short f2bf(float x) {
  union { float f; unsigned int u; } v; v.f = x;
  unsigned int r = v.u + 0x7FFFu + ((v.u >> 16) & 1u);  // RNE
  return (unsigned short)(r >> 16);
}

__device__ __forceinline__ float fexp2(float x) {
#if __has_builtin(__builtin_amdgcn_exp2f)
  return __builtin_amdgcn_exp2f(x);
#else
  return exp2f(x);
#endif
}

// ---- prep: transpose weights to N-major bf16 (Wt[n][k] = W[k][n]) ----
__global__ __launch_bounds__(256) void prep_w(const float* __restrict__ Wq, const float* __restrict__ Wk,
                                              const float* __restrict__ Wv, const float* __restrict__ Wo,
                                              unsigned short* __restrict__ Wqt, unsigned short* __restrict__ Wkt,
                                              unsigned short* __restrict__ Wvt, unsigned short* __restrict__ Wot) {
  int i = blockIdx.x * 256 + threadIdx.x;     // < 4*512*512
  int wsel = i >> 18;
  int r = i & 262143;
  int k = r >> 9, n = r & 511;
  const float* W = (wsel == 0) ? Wq : (wsel == 1) ? Wk : (wsel == 2) ? Wv : Wo;
  unsigned short* Wt = (wsel == 0) ? Wqt : (wsel == 1) ? Wkt : (wsel == 2) ? Wvt : Wot;
  Wt[n * 512 + k] = f2bf(W[r]);
}

// ---- Q projection, fused input prep: Qb = bf16((feats + pos_emb[coords//8]) @ Wq) ----
__global__ __launch_bounds__(256) void gemm_q(const float* __restrict__ feats,
                                              const int* __restrict__ coords,
                                              const float* __restrict__ pos_emb,
                                              const unsigned short* __restrict__ Bt,
                                              unsigned short* __restrict__ C) {
  __shared__ unsigned short As[64][40];
  __shared__ unsigned short Bs[128][40];
  __shared__ int pidx[64];
  const int t = threadIdx.x, l = t & 63, wid = t >> 6;
  const int wr = (wid >> 1) << 5;   // 0 / 32
  const int wc = (wid & 1) << 6;    // 0 / 64
  const long tm = (long)blockIdx.x * 64;
  const long tn = (long)blockIdx.y * 128;
  if (t < 64) {
    long q = tm + t;
    pidx[t] = ((coords[2 * q] >> 3) << 6) + (coords[2 * q + 1] >> 3);
  }
  __syncthreads();
  f32x4 acc[2][4] = {};
  const int lr = l & 15, lk = (l >> 4) << 3;
  for (int k0 = 0; k0 < 512; k0 += 32) {
#pragma unroll
    for (int p = 0; p < 2; ++p) {               // A: 64x32 f32 + pos add
      int e = t + (p << 8);
      int row = e >> 3, kg = (e & 7) << 2;
      float4 a = *(const float4*)(feats + (tm + row) * 512 + k0 + kg);
      float4 pv = *(const float4*)(pos_emb + (size_t)pidx[row] * 512 + k0 + kg);
      uint2 o;
      o.x = (unsigned)f2bf(a.x + pv.x) | ((unsigned)f2bf(a.y + pv.y) << 16);
      o.y = (unsigned)f2bf(a.z + pv.z) | ((unsigned)f2bf(a.w + pv.w) << 16);
      *(uint2*)(&As[row][kg]) = o;
    }
#pragma unroll
    for (int p = 0; p < 2; ++p) {               // B: 128x32 bf16
      int e = t + (p << 8);
      int row = e >> 2, kg = (e & 3) << 3;
      *(int4*)(&Bs[row][kg]) = *(const int4*)(Bt + (tn + row) * 512 + k0 + kg);
    }
    __syncthreads();
    bf16x8 af[2], bfr[4];
#pragma unroll
    for (int i = 0; i < 2; ++i) af[i]  = *(const bf16x8*)(&As[wr + i * 16 + lr][lk]);
#pragma unroll
    for (int i = 0; i < 4; ++i) bfr[i] = *(const bf16x8*)(&Bs[wc + i * 16 + lr][lk]);
#pragma unroll
    for (int mi = 0; mi < 2; ++mi)
#pragma unroll
      for (int ni = 0; ni < 4; ++ni)
        acc[mi][ni] = __builtin_amdgcn_mfma_f32_16x16x32_bf16(af[mi], bfr[ni], acc[mi][ni], 0, 0, 0);
    __syncthreads();
  }
  const int lq = (l >> 4) << 2;
#pragma unroll
  for (int mi = 0; mi < 2; ++mi)
#pragma unroll
    for (int ni = 0; ni < 4; ++ni) {
      long col = tn + wc + ni * 16 + lr;
      long r0 = tm + wr + mi * 16 + lq;
#pragma unroll
      for (int r = 0; r < 4; ++r)
        C[(r0 + r) * 512 + col] = f2bf(acc[mi][ni][r]);
    }
}

// ---- fused K|V projection with input prep; V written transposed ----
__global__ __launch_bounds__(256) void gemm_kv(const float* __restrict__ ctx,
                                               const float* __restrict__ ctx_pos,
                                               const unsigned short* __restrict__ Wkt,
                                               const unsigned short* __restrict__ Wvt,
                                               unsigned short* __restrict__ Kb,
                                               unsigned short* __restrict__ Vt) {
  __shared__ unsigned short As[64][40];
  __shared__ unsigned short Bs[128][40];
  const int t = threadIdx.x, l = t & 63, wid = t >> 6;
  const int wr = (wid >> 1) << 5;
  const int wc = (wid & 1) << 6;
  const long tm = (long)blockIdx.x * 64;
  const bool isV = blockIdx.y >= 4;
  const int nt = isV ? (blockIdx.y - 4) : blockIdx.y;
  const unsigned short* Bt = (isV ? Wvt : Wkt) + (long)nt * 128 * 512;
  f32x4 acc[2][4] = {};
  const int lr = l & 15, lk = (l >> 4) << 3;
  for (int k0 = 0; k0 < 512; k0 += 32) {
#pragma unroll
    for (int p = 0; p < 2; ++p) {               // A: ctx + ctx_pos
      int e = t + (p << 8);
      int row = e >> 3, kg = (e & 7) << 2;
      long ar = tm + row;
      float4 a = *(const float4*)(ctx + ar * 512 + k0 + kg);
      float4 pv = *(const float4*)(ctx_pos + (size_t)(ar & 1023) * 512 + k0 + kg);
      uint2 o;
      o.x = (unsigned)f2bf(a.x + pv.x) | ((unsigned)f2bf(a.y + pv.y) << 16);
      o.y = (unsigned)f2bf(a.z + pv.z) | ((unsigned)f2bf(a.w + pv.w) << 16);
      *(uint2*)(&As[row][kg]) = o;
    }
#pragma unroll
    for (int p = 0; p < 2; ++p) {
      int e = t + (p << 8);
      int row = e >> 2, kg = (e & 3) << 3;
      *(int4*)(&Bs[row][kg]) = *(const int4*)(Bt + (long)row * 512 + k0 + kg);
    }
    __syncthreads();
    bf16x8 af[2], bfr[4];
#pragma unroll
    for (int i = 0; i < 2; ++i) af[i]  = *(const bf16x8*)(&As[wr + i * 16 + lr][lk]);
#pragma unroll
    for (int i = 0; i < 4; ++i) bfr[i] = *(const bf16x8*)(&Bs[wc + i * 16 + lr][lk]);
#pragma unroll
    for (int mi = 0; mi < 2; ++mi)
#pragma unroll
      for (int ni = 0; ni < 4; ++ni)
        acc[mi][ni] = __builtin_amdgcn_mfma_f32_16x16x32_bf16(af[mi], bfr[ni], acc[mi][ni], 0, 0, 0);
    __syncthreads();
  }
  const int lq = (l >> 4) << 2;
#pragma unroll
  for (int mi = 0; mi < 2; ++mi)
#pragma unroll
    for (int ni = 0; ni < 4; ++ni) {
      int cn = nt * 128 + wc + ni * 16 + lr;      // 0..511 within K or V
      long r0 = tm + wr + mi * 16 + lq;
      if (!isV) {
#pragma unroll
        for (int r = 0; r < 4; ++r)
          Kb[(r0 + r) * 512 + cn] = f2bf(acc[mi][ni][r]);
      } else {
        int h = cn >> 6, d = cn & 63;
#pragma unroll
        for (int r = 0; r < 4; ++r) {
          long row = r0 + r;
          int b = (int)(row >> 10), j = (int)(row & 1023);
          Vt[(((long)(b * 8 + h) * 64) + d) * 1024 + j] = f2bf(acc[mi][ni][r]);
        }
      }
    }
}

// ---- MFMA masked flash attention: 32 rows/wave, 4 waves, grid (16, 32) ----
// K-fragments double-buffered in registers (prefetch next tile during current).
__global__ __launch_bounds__(256) void attn_mfma(const unsigned short* __restrict__ Qb,
                                                 const unsigned short* __restrict__ Kb,
                                                 const unsigned short* __restrict__ Vt,
                                                 const int* __restrict__ coords,
                                                 unsigned short* __restrict__ Abf) {
  __shared__ unsigned short Plds[4][32][72];
  const int t = threadIdx.x;
  const int w = t >> 6, l = t & 63;
  const int g = l >> 4, lc = l & 15;
  const int bh = blockIdx.y, b = bh >> 3, h = bh & 7;
  const long qrow0 = (long)b * 2048 + blockIdx.x * 128 + w * 32;

  // 32-bit row/col bitmasks for the 8 query-rows this lane reduces
  int rm[8], cm[8];
#pragma unroll
  for (int qf = 0; qf < 2; ++qf)
#pragma unroll
    for (int r = 0; r < 4; ++r) {
      long qg = qrow0 + qf * 16 + g * 4 + r;
      int cr = (int)rintf((float)coords[2 * qg] * 0.0625f);      // round-half-even = jnp.round
      int cc = (int)rintf((float)coords[2 * qg + 1] * 0.0625f);
      int rlo = max(0, cr - 8), rhi = min(31, cr + 8);
      int clo = max(0, cc - 8), chi = min(31, cc + 8);
      rm[qf * 4 + r] = (int)((((unsigned)1 << (rhi - rlo + 1)) - 1) << rlo);
      cm[qf * 4 + r] = (int)((((unsigned)1 << (chi - clo + 1)) - 1) << clo);
    }

  bf16x8 qfr[2][2];
#pragma unroll
  for (int qf = 0; qf < 2; ++qf)
#pragma unroll
    for (int dc = 0; dc < 2; ++dc)
      qfr[qf][dc] = *(const bf16x8*)(Qb + (qrow0 + qf * 16 + lc) * 512 + h * 64 + dc * 32 + g * 8);

  f32x4 po[2][4] = {};
  float m_run[8], l_run[8];
#pragma unroll
  for (int i = 0; i < 8; ++i) { m_run[i] = -1e30f; l_run[i] = 0.0f; }

  const unsigned short* Kbb = Kb + ((long)b * 1024) * 512 + h * 64;
  const unsigned short* Vtb = Vt + ((long)bh * 64) * 1024;

  auto LOADK = [&](bf16x8 (&kf)[4][2], int kb) {
#pragma unroll
    for (int kfi = 0; kfi < 4; ++kfi)
#pragma unroll
      for (int dc = 0; dc < 2; ++dc)
        kf[kfi][dc] = *(const bf16x8*)(Kbb + (long)(kb + kfi * 16 + lc) * 512 + dc * 32 + g * 8);
  };

  auto TILE = [&](bf16x8 (&kc)[4][2], int kb, bf16x8 (&kn)[4][2], int kbn) {
    // V^T fragments for this tile (consumed last -> latency hides under softmax)
    bf16x8 vfr[4][2];
#pragma unroll
    for (int df = 0; df < 4; ++df)
#pragma unroll
      for (int kc2 = 0; kc2 < 2; ++kc2)
        vfr[df][kc2] = *(const bf16x8*)(Vtb + (long)(df * 16 + lc) * 1024 + kb + kc2 * 32 + g * 8);

    // S = Q K^T (K already in registers)
    f32x4 sv[2][4];
#pragma unroll
    for (int qf = 0; qf < 2; ++qf)
#pragma unroll
      for (int kf = 0; kf < 4; ++kf) {
        f32x4 a = {};
        a = __builtin_amdgcn_mfma_f32_16x16x32_bf16(qfr[qf][0], kc[kf][0], a, 0, 0, 0);
        a = __builtin_amdgcn_mfma_f32_16x16x32_bf16(qfr[qf][1], kc[kf][1], a, 0, 0, 0);
        sv[qf][kf] = a;
      }

    // prefetch next tile's K fragments (used next tile -> latency hidden)
    if (kbn < 1024) LOADK(kn, kbn);

    // mask (bitmask) + scale into exp2 domain
#pragma unroll
    for (int kf = 0; kf < 4; ++kf) {
      int j = kb + kf * 16 + lc;
      int jr = j >> 5, jc = j & 31;
#pragma unroll
      for (int qf = 0; qf < 2; ++qf)
#pragma unroll
        for (int r = 0; r < 4; ++r) {
          bool ok = ((rm[qf * 4 + r] >> jr) & (cm[qf * 4 + r] >> jc) & 1) != 0;
          sv[qf][kf][r] = ok ? sv[qf][kf][r] * SCL : -3.0e38f;
        }
    }

    // online softmax (exp2 domain)
#pragma unroll
    for (int qf = 0; qf < 2; ++qf)
#pragma unroll
      for (int r = 0; r < 4; ++r) {
        int idx = qf * 4 + r;
        float tm4 = fmaxf(fmaxf(sv[qf][0][r], sv[qf][1][r]), fmaxf(sv[qf][2][r], sv[qf][3][r]));
        tm4 = fmaxf(tm4, __shfl_xor(tm4, 1));
        tm4 = fmaxf(tm4, __shfl_xor(tm4, 2));
        tm4 = fmaxf(tm4, __shfl_xor(tm4, 4));
        tm4 = fmaxf(tm4, __shfl_xor(tm4, 8));
        float mn = fmaxf(m_run[idx], tm4);
        float sc = fexp2(m_run[idx] - mn);
        m_run[idx] = mn;
        float ps = 0.0f;
#pragma unroll
        for (int kf = 0; kf < 4; ++kf) {
          float pe = fexp2(sv[qf][kf][r] - mn);
          sv[qf][kf][r] = pe;
          ps += pe;
        }
        ps += __shfl_xor(ps, 1); ps += __shfl_xor(ps, 2);
        ps += __shfl_xor(ps, 4); ps += __shfl_xor(ps, 8);
        l_run[idx] = l_run[idx] * sc + ps;
#pragma unroll
        for (int df = 0; df < 4; ++df) po[qf][df][r] *= sc;
      }

    // P (C-layout) -> LDS -> A-layout (wave-private, no barrier)
#pragma unroll
    for (int qf = 0; qf < 2; ++qf)
#pragma unroll
      for (int kf = 0; kf < 4; ++kf)
#pragma unroll
        for (int r = 0; r < 4; ++r)
          Plds[w][qf * 16 + g * 4 + r][kf * 16 + lc] = f2bf(sv[qf][kf][r]);

#pragma unroll
    for (int qf = 0; qf < 2; ++qf) {
      bf16x8 pa[2];
#pragma unroll
      for (int kc2 = 0; kc2 < 2; ++kc2)
        pa[kc2] = *(const bf16x8*)(&Plds[w][qf * 16 + lc][kc2 * 32 + g * 8]);
#pragma unroll
      for (int df = 0; df < 4; ++df) {
        po[qf][df] = __builtin_amdgcn_mfma_f32_16x16x32_bf16(pa[0], vfr[df][0], po[qf][df], 0, 0, 0);
        po[qf][df] = __builtin_amdgcn_mfma_f32_16x16x32_bf16(pa[1], vfr[df][1], po[qf][df], 0, 0, 0);
      }
    }
  };

  bf16x8 kA[4][2], kB[4][2];
  LOADK(kA, 0);
  for (int kb = 0; kb < 1024; kb += 128) {
    TILE(kA, kb, kB, kb + 64);
    TILE(kB, kb + 64, kA, kb + 128);
  }

  // epilogue: normalize, write bf16
#pragma unroll
  for (int qf = 0; qf < 2; ++qf)
#pragma unroll
    for (int r = 0; r < 4; ++r) {
      float inv = 1.0f / l_run[qf * 4 + r];
      long qr = qrow0 + qf * 16 + g * 4 + r;
#pragma unroll
      for (int df = 0; df < 4; ++df)
        Abf[qr * 512 + h * 64 + df * 16 + lc] = f2bf(po[qf][df][r] * inv);
    }
}

// ---- output projection: out = Abf @ Wot^T + bo (fp32 out) ----
__global__ __launch_bounds__(256) void gemm_o(const unsigned short* __restrict__ A,
                                              const unsigned short* __restrict__ Bt,
                                              float* __restrict__ C,
                                              const float* __restrict__ bias) {
  __shared__ unsigned short As[64][40];
  __shared__ unsigned short Bs[128][40];
  const int t = threadIdx.x, l = t & 63, wid = t >> 6;
  const int wr = (wid >> 1) << 5;
  const int wc = (wid & 1) << 6;
  const long tm = (long)blockIdx.x * 64;
  const long tn = (long)blockIdx.y * 128;
  f32x4 acc[2][4] = {};
  const int lr = l & 15, lk = (l >> 4) << 3;
  for (int k0 = 0; k0 < 512; k0 += 32) {
    {
      int e = t;                                // A: 64x32 bf16, 1 pass int4
      int row = e >> 2, kg = (e & 3) << 3;
      if (row < 64)
        *(int4*)(&As[row][kg]) = *(const int4*)(A + (tm + row) * 512 + k0 + kg);
    }
#pragma unroll
    for (int p = 0; p < 2; ++p) {
      int e = t + (p << 8);
      int row = e >> 2, kg = (e & 3) << 3;
      *(int4*)(&Bs[row][kg]) = *(const int4*)(Bt + (tn + row) * 512 + k0 + kg);
    }
    __syncthreads();
    bf16x8 af[2], bfr[4];
#pragma unroll
    for (int i = 0; i < 2; ++i) af[i]  = *(const bf16x8*)(&As[wr + i * 16 + lr][lk]);
#pragma unroll
    for (int i = 0; i < 4; ++i) bfr[i] = *(const bf16x8*)(&Bs[wc + i * 16 + lr][lk]);
#pragma unroll
    for (int mi = 0; mi < 2; ++mi)
#pragma unroll
      for (int ni = 0; ni < 4; ++ni)
        acc[mi][ni] = __builtin_amdgcn_mfma_f32_16x16x32_bf16(af[mi], bfr[ni], acc[mi][ni], 0, 0, 0);
    __syncthreads();
  }
  const int lq = (l >> 4) << 2;
#pragma unroll
  for (int mi = 0; mi < 2; ++mi)
#pragma unroll
    for (int ni = 0; ni < 4; ++ni) {
      long col = tn + wc + ni * 16 + lr;
      float bv = bias[col];
      long r0 = tm + wr + mi * 16 + lq;
#pragma unroll
      for (int r = 0; r < 4; ++r)
        C[(r0 + r) * 512 + col] = acc[mi][ni][r] + bv;
    }
}

extern "C" void kernel_launch(void* const* d_in, const int* in_sizes, int n_in,
                              void* d_out, int out_size, void* d_ws, size_t ws_size,
                              hipStream_t stream) {
  (void)in_sizes; (void)n_in; (void)out_size; (void)ws_size;
  const float* feats   = (const float*)d_in[0];
  const int*   coords  = (const int*)d_in[1];
  const float* ctx     = (const float*)d_in[2];
  const float* Wq      = (const float*)d_in[3];
  const float* Wk      = (const float*)d_in[4];
  const float* Wv      = (const float*)d_in[5];
  const float* Wo      = (const float*)d_in[6];
  const float* bo      = (const float*)d_in[7];
  const float* pos_emb = (const float*)d_in[8];
  const float* ctx_pos = (const float*)d_in[9];
  float* out = (float*)d_out;
  char* ws = (char*)d_ws;

  unsigned short* Wqt = (unsigned short*)(ws);              //   524,288
  unsigned short* Wkt = (unsigned short*)(ws + 524288);
  unsigned short* Wvt = (unsigned short*)(ws + 1048576);
  unsigned short* Wot = (unsigned short*)(ws + 1572864);
  unsigned short* Qb  = (unsigned short*)(ws + 2097152);    // 8,388,608
  unsigned short* Kb  = (unsigned short*)(ws + 10485760);   // 4,194,304
  unsigned short* Vt  = (unsigned short*)(ws + 14680064);   // 4,194,304
  unsigned short* Abf = (unsigned short*)(ws + 18874368);   // 8,388,608 (end 27,262,976)

  prep_w <<<4096, 256, 0, stream>>>(Wq, Wk, Wv, Wo, Wqt, Wkt, Wvt, Wot);

  gemm_q <<<dim3(128, 4), 256, 0, stream>>>(feats, coords, pos_emb, Wqt, Qb);
  gemm_kv<<<dim3(64, 8),  256, 0, stream>>>(ctx, ctx_pos, Wkt, Wvt, Kb, Vt);

  attn_mfma<<<dim3(16, 32), 256, 0, stream>>>(Qb, Kb, Vt, coords, Abf);

  gemm_o <<<dim3(128, 4), 256, 0, stream>>>(Abf, Wot, out, bo);
}